// Round 11
// baseline (1859.548 us; speedup 1.0000x reference)
//
#include <hip/hip_runtime.h>

typedef unsigned int uint;
typedef _Float16 f16;
typedef _Float16 f16x4 __attribute__((ext_vector_type(4)));
typedef _Float16 f16x8 __attribute__((ext_vector_type(8)));
typedef float f32x4 __attribute__((ext_vector_type(4)));

#define B_ 64
#define T_ 1024
#define I_ 128
#define H_ 256
#define NWK 64

// ---------------- device: one 32x128 Xg GEMM tile (R10-proven shape) ------------------
// 256 staging threads, 4 MFMA waves.  KA = 128 (layer-1 x, fp32 A) or 256 (y1h, f16 A).
template<int KA, bool AF32>
__device__ __forceinline__ void gemm_tile(const void* __restrict__ Av,
    const f16* __restrict__ Bt, const float* __restrict__ bf, const float* __restrict__ bc,
    f16* __restrict__ Xg, int m0, int n0, f16 (*As)[72], f16 (*Bs)[72]) {
  const int tid = threadIdx.x, lane = tid & 63, wid = tid >> 6;
  const bool act = tid < 256;
  f32x4 zero4 = {0.f, 0.f, 0.f, 0.f};
  f32x4 acc[2][2];
  #pragma unroll
  for (int i = 0; i < 2; ++i)
    #pragma unroll
    for (int j = 0; j < 2; ++j) acc[i][j] = zero4;
  const int arow = tid >> 3, aq = tid & 7;          // A: 32 rows x 8 slices of 8
  const int r2 = (tid & 255) >> 1, hh = tid & 1;    // B: 128 rows x 2 halves of 32
  for (int kb = 0; kb < KA / 64; ++kb) {
    const int k0 = kb * 64;
    if (kb) __syncthreads();
    if (act) {
      if (AF32) {
        const float* srcA = (const float*)Av + (size_t)(m0 + arow) * KA + k0 + aq * 8;
        float4 v0 = *(const float4*)srcA;
        float4 v1 = *(const float4*)(srcA + 4);
        f16x8 p = { (f16)v0.x, (f16)v0.y, (f16)v0.z, (f16)v0.w,
                    (f16)v1.x, (f16)v1.y, (f16)v1.z, (f16)v1.w };
        *(f16x8*)&As[arow][aq * 8] = p;
      } else {
        const f16* srcA = (const f16*)Av + (size_t)(m0 + arow) * KA + k0 + aq * 8;
        *(uint4*)&As[arow][aq * 8] = *(const uint4*)srcA;
      }
      const f16* srcB = Bt + (size_t)(n0 + r2) * KA + k0 + hh * 32;
      #pragma unroll
      for (int i = 0; i < 4; ++i)
        *(uint4*)&Bs[r2][hh * 32 + i * 8] = *(const uint4*)(srcB + i * 8);
    }
    __syncthreads();
    if (wid < 4) {
      #pragma unroll
      for (int kt = 0; kt < 2; ++kt) {
        f16x8 af[2], bfr[2];
        #pragma unroll
        for (int i = 0; i < 2; ++i)
          af[i] = *(const f16x8*)&As[i * 16 + (lane & 15)][kt * 32 + (lane >> 4) * 8];
        #pragma unroll
        for (int j = 0; j < 2; ++j)
          bfr[j] = *(const f16x8*)&Bs[wid * 32 + j * 16 + (lane & 15)][kt * 32 + (lane >> 4) * 8];
        #pragma unroll
        for (int i = 0; i < 2; ++i)
          #pragma unroll
          for (int j = 0; j < 2; ++j)
            acc[i][j] = __builtin_amdgcn_mfma_f32_16x16x32_f16(af[i], bfr[j], acc[i][j], 0, 0, 0);
      }
    }
  }
  if (wid < 4) {
    const float* bias = (n0 < 256) ? bf : bc;
    #pragma unroll
    for (int j = 0; j < 2; ++j) {
      const int gn = n0 + wid * 32 + j * 16 + (lane & 15);
      const float bv = bias[gn & 255];
      #pragma unroll
      for (int i = 0; i < 2; ++i) {
        #pragma unroll
        for (int reg = 0; reg < 4; ++reg) {
          const int gm = m0 + i * 16 + (lane >> 4) * 4 + reg;
          Xg[(size_t)gm * 512 + gn] = (f16)(acc[i][j][reg] + bv);
        }
      }
    }
  }
  __syncthreads();   // As/Bs safe for next tile
}

// ---------------- device: rec inner loop (R10-proven) + gates/publish -----------------
// Weights loaded DIRECTLY from Wf/Wc (strided one-time gather; replaces UT prep).
// done_gate: wait done_gate[c]==64 before prefetching into chunk c (L1: done1, L2: done2).
// start_chunk: L1 starts on chunk 0; L2 starts on chunk 1 (2-chunk lag -> after start,
// every gate is already open: kills R10's ~5us-per-chunk burst stall, ~150us total).
// prog_pub (L1 only): publish t+1 every 32 steps after vmcnt drain (release, agent).
__device__ __forceinline__ void rec_core(const float* __restrict__ Wf,
    const float* __restrict__ Wc, const int DIN,
    f16* __restrict__ Xg, float* __restrict__ yf, f16* __restrict__ yh,
    float* __restrict__ hid, const int g, int* prog_pub, int* done_gate,
    const int start_chunk, f16 (*hbuf)[16][264]) {
  const int tid = threadIdx.x;
  const int lane = tid & 63, w = tid >> 6;
  const int lr = lane & 15, lg = lane >> 4;
  const int m0 = g * 16;

  const int nt[4] = { 32 * w, 32 * w + 16, 256 + 32 * w, 256 + 32 * w + 16 };

  // weight fragments straight from W: uw[tt][kf][j] = (f16)W[(DIN+k)*256 + col],
  // k = kf*32 + lg*8 + j, col = (nt&255) + lr.  Coalesced across lr.
  f16x8 uw[4][8];
  #pragma unroll
  for (int tt = 0; tt < 4; ++tt) {
    const float* Wsel = (nt[tt] < 256) ? Wf : Wc;
    const int col = (nt[tt] & 255) + lr;
    #pragma unroll
    for (int kf = 0; kf < 8; ++kf) {
      __align__(16) f16 tmp[8];
      #pragma unroll
      for (int j = 0; j < 8; ++j)
        tmp[j] = (f16)Wsel[(size_t)(DIN + kf * 32 + lg * 8 + j) * 256 + col];
      uw[tt][kf] = *(const f16x8*)tmp;
    }
  }
  #pragma unroll
  for (int tt = 0; tt < 4; ++tt)
    #pragma unroll
    for (int kf = 0; kf < 8; ++kf)
      asm volatile("" : "+v"(uw[tt][kf]));

  {
    uint* hz = (uint*)&hbuf[0][0][0];
    for (int i = tid; i < 2112; i += 512) hz[i] = 0u;
  }

  // initial gate: start_chunk's tiles all written
  if (tid == 0)
    while (__hip_atomic_load(&done_gate[start_chunk], __ATOMIC_ACQUIRE, __HIP_MEMORY_SCOPE_AGENT) < 64)
      __builtin_amdgcn_s_sleep(8);
  __syncthreads();

  const f16* xp[4];
  #pragma unroll
  for (int tt = 0; tt < 4; ++tt)
    xp[tt] = Xg + ((size_t)(m0 + lr) * T_) * 512 + nt[tt] + 4 * lg;

  float hreg[2][4] = {{0.f,0.f,0.f,0.f},{0.f,0.f,0.f,0.f}};
  f16x4 xcur[4];
  #pragma unroll
  for (int tt = 0; tt < 4; ++tt) xcur[tt] = *(const f16x4*)xp[tt];

  const size_t ybase = (size_t)(m0 + lr) * T_ * H_;
  const int ycol0 = 32 * w + 4 * lg;

  __syncthreads();

  #pragma unroll 1
  for (int t = 0; t < T_; ++t) {
    // gate the NEXT 32-step chunk before prefetching into it
    {
      const int tp1 = t + 1;
      if ((tp1 & 31) == 0 && (tp1 >> 5) < 32) {
        if (tid == 0)
          while (__hip_atomic_load(&done_gate[tp1 >> 5], __ATOMIC_ACQUIRE, __HIP_MEMORY_SCOPE_AGENT) < 64)
            __builtin_amdgcn_s_sleep(8);
        __syncthreads();
      }
    }

    const int tn = (t + 1 < T_) ? t + 1 : t;
    f16x4 xn[4];
    #pragma unroll
    for (int tt = 0; tt < 4; ++tt) xn[tt] = *(const f16x4*)(xp[tt] + (size_t)tn * 512);

    const f16* hrow = &hbuf[t & 1][lr][0];
    f16x8 hf[8];
    #pragma unroll
    for (int kf = 0; kf < 8; ++kf)
      hf[kf] = *(const f16x8*)(hrow + kf * 32 + lg * 8);

    f32x4 acc[4];
    #pragma unroll
    for (int tt = 0; tt < 4; ++tt) acc[tt] = (f32x4){0.f, 0.f, 0.f, 0.f};
    #pragma unroll
    for (int kf = 0; kf < 8; ++kf)
      #pragma unroll
      for (int tt = 0; tt < 4; ++tt)
        acc[tt] = __builtin_amdgcn_mfma_f32_16x16x32_f16(uw[tt][kf], hf[kf], acc[tt], 0, 0, 0);

    f16x4 hn4[2];
    #pragma unroll
    for (int p = 0; p < 2; ++p) {
      #pragma unroll
      for (int r = 0; r < 4; ++r) {
        float pf = acc[p][r]     + (float)xcur[p][r];
        float pc = acc[2 + p][r] + (float)xcur[2 + p][r];
        float fg = __builtin_amdgcn_rcpf(1.f + __expf(-pf));
        float e2 = __expf(2.f * pc);
        float cc = 1.f - 2.f * __builtin_amdgcn_rcpf(e2 + 1.f);
        float hn = cc + fg * (hreg[p][r] - cc);
        hreg[p][r] = hn;
        hn4[p][r] = (f16)hn;
      }
      *(f16x4*)&hbuf[(t + 1) & 1][lr][ycol0 + 16 * p] = hn4[p];
    }
    if (yh) {
      #pragma unroll
      for (int p = 0; p < 2; ++p)
        *(f16x4*)(yh + ybase + (size_t)t * H_ + ycol0 + 16 * p) = hn4[p];
    }
    if (yf) {
      #pragma unroll
      for (int p = 0; p < 2; ++p) {
        float4 yv = make_float4(hreg[p][0], hreg[p][1], hreg[p][2], hreg[p][3]);
        *(float4*)(yf + ybase + (size_t)t * H_ + ycol0 + 16 * p) = yv;
      }
    }
    if (t == T_ - 1) {
      #pragma unroll
      for (int p = 0; p < 2; ++p) {
        float4 hv = make_float4(hreg[p][0], hreg[p][1], hreg[p][2], hreg[p][3]);
        *(float4*)(hid + (size_t)(m0 + lr) * H_ + ycol0 + 16 * p) = hv;
      }
    }

    asm volatile("s_waitcnt lgkmcnt(0)" ::: "memory");
    __builtin_amdgcn_s_barrier();
    asm volatile("" ::: "memory");

    if (prog_pub && ((t & 31) == 31)) {
      asm volatile("s_waitcnt vmcnt(0)" ::: "memory");
      __syncthreads();
      if (tid == 0)
        __hip_atomic_store(prog_pub, t + 1, __ATOMIC_RELEASE, __HIP_MEMORY_SCOPE_AGENT);
    }

    #pragma unroll
    for (int tt = 0; tt < 4; ++tt) xcur[tt] = xn[tt];
  }
}

// ---------------- device: worker — prep + Xg1 producer + Xg2 producer -----------------
// Phase P: prep Wx1T/Wx2T slices, barrier among 64 workers (prep_done).
// Main loop c=0..31: (a) Xg1 tiles for chunks 2c,2c+1 (ungated; keeps L1 a full
// chunk-pair ahead -> L1 never starves even while workers block on prog), then
// (b) prog-gated Xg2 tiles for chunk c (in-place over Xg; L1 is provably past).
// Tile ownership fixed per worker -> Xg1-then-Xg2 writes to the same tile are
// program-ordered within one block, separated by vmcnt(0) drains.
__device__ __forceinline__ void worker(const int wk, const float* __restrict__ x,
    const float* __restrict__ Wf1, const float* __restrict__ bf1,
    const float* __restrict__ Wc1, const float* __restrict__ bc1,
    const float* __restrict__ Wf2, const float* __restrict__ bf2,
    const float* __restrict__ Wc2, const float* __restrict__ bc2,
    f16* __restrict__ Wx1T, f16* __restrict__ Wx2T,
    const f16* __restrict__ y1h, f16* __restrict__ Xg,
    int* prep_done, int* prog, int* done1, int* done2,
    f16 (*As)[72], f16 (*Bs)[72]) {
  const int tid = threadIdx.x;

  // phase P: prep 3072 f16 of {Wx1T | Wx2T}
  for (int i = tid; i < 3072; i += 512) {
    const int o = wk * 3072 + i;
    if (o < 65536) {
      const int n = o >> 7, k = o & 127;
      Wx1T[o] = (f16)(((n < 256) ? Wf1 : Wc1)[k * 256 + (n & 255)]);
    } else {
      const int o2 = o - 65536;
      const int n = o2 >> 8, k = o2 & 255;
      Wx2T[o2] = (f16)(((n < 256) ? Wf2 : Wc2)[k * 256 + (n & 255)]);
    }
  }
  asm volatile("s_waitcnt vmcnt(0)" ::: "memory");
  __syncthreads();
  if (tid == 0) {
    __hip_atomic_fetch_add(prep_done, 1, __ATOMIC_ACQ_REL, __HIP_MEMORY_SCOPE_AGENT);
    while (__hip_atomic_load(prep_done, __ATOMIC_ACQUIRE, __HIP_MEMORY_SCOPE_AGENT) < NWK)
      __builtin_amdgcn_s_sleep(2);
  }
  __syncthreads();

  #pragma unroll 1
  for (int c = 0; c < 32; ++c) {
    if (c < 16) {
      #pragma unroll 1
      for (int cc = 2 * c; cc <= 2 * c + 1; ++cc) {
        #pragma unroll 1
        for (int s = 0; s < 4; ++s) {
          const int rem = (wk + 64 * s) & 255;
          const int b = rem >> 2, n = rem & 3, g1 = b >> 4;
          gemm_tile<128, true>(x, Wx1T, bf1, bc1, Xg, b * 1024 + cc * 32, n * 128, As, Bs);
          asm volatile("s_waitcnt vmcnt(0)" ::: "memory");
          __syncthreads();
          if (tid == 0)
            __hip_atomic_fetch_add(&done1[g1 * 32 + cc], 1, __ATOMIC_ACQ_REL, __HIP_MEMORY_SCOPE_AGENT);
        }
      }
    }
    #pragma unroll 1
    for (int s = 0; s < 4; ++s) {
      const int rem = (wk + 64 * s) & 255;
      const int b = rem >> 2, n = rem & 3, g1 = b >> 4;
      if (tid == 0)
        while (__hip_atomic_load(&prog[g1], __ATOMIC_ACQUIRE, __HIP_MEMORY_SCOPE_AGENT) < c * 32 + 32)
          __builtin_amdgcn_s_sleep(8);
      __syncthreads();
      gemm_tile<256, false>(y1h, Wx2T, bf2, bc2, Xg, b * 1024 + c * 32, n * 128, As, Bs);
      asm volatile("s_waitcnt vmcnt(0)" ::: "memory");
      __syncthreads();
      if (tid == 0)
        __hip_atomic_fetch_add(&done2[g1 * 32 + c], 1, __ATOMIC_ACQ_REL, __HIP_MEMORY_SCOPE_AGENT);
    }
  }
}

// ---------------- fused everything: 4 L1-rec + 64 workers + 4 L2-rec ------------------
// DAG: workers(Xg1) -> done1 -> L1 -> prog -> workers(Xg2) -> done2 -> L2.
// 72 blocks < 256 CUs -> all resident; acyclic; agent-scope release/acquire.
__global__ __launch_bounds__(512, 1) void fused(const float* __restrict__ x,
    const float* __restrict__ Wf1, const float* __restrict__ bf1,
    const float* __restrict__ Wc1, const float* __restrict__ bc1,
    const float* __restrict__ Wf2, const float* __restrict__ bf2,
    const float* __restrict__ Wc2, const float* __restrict__ bc2,
    f16* __restrict__ Xg, f16* __restrict__ Wx1T, f16* __restrict__ Wx2T,
    f16* __restrict__ y1h, float* __restrict__ y2,
    float* __restrict__ hid1, float* __restrict__ hid2, int* __restrict__ sync) {
  __shared__ __align__(16) f16 hbuf[2][16][264];
  __shared__ __align__(16) f16 As[32][72];
  __shared__ __align__(16) f16 Bs[128][72];
  int* prep_done = sync;       // [1]   worker prep barrier (target 64)
  int* prog  = sync + 1;       // [4]   L1 step progress per row-group
  int* done1 = sync + 5;       // [4][32] Xg1 tiles done per (group, chunk), target 64
  int* done2 = sync + 133;     // [4][32] Xg2 tiles done per (group, chunk), target 64
  const int bid = blockIdx.x;

  if (bid < 4) {
    rec_core(Wf1, Wc1, 128, Xg, nullptr, y1h, hid1, bid,
             &prog[bid], &done1[bid * 32], 0, hbuf);
  } else if (bid < 68) {
    worker(bid - 4, x, Wf1, bf1, Wc1, bc1, Wf2, bf2, Wc2, bc2,
           Wx1T, Wx2T, y1h, Xg, prep_done, prog, done1, done2, As, Bs);
  } else {
    const int g = bid - 68;
    rec_core(Wf2, Wc2, 256, Xg, y2, nullptr, hid2, g,
             nullptr, &done2[g * 32], 1, hbuf);
  }
}

extern "C" void kernel_launch(void* const* d_in, const int* in_sizes, int n_in,
                              void* d_out, int out_size, void* d_ws, size_t ws_size,
                              hipStream_t stream) {
  (void)in_sizes; (void)n_in; (void)out_size; (void)ws_size;
  const float* x   = (const float*)d_in[0];
  const float* Wf1 = (const float*)d_in[1];
  const float* bf1 = (const float*)d_in[2];
  const float* Wc1 = (const float*)d_in[3];
  const float* bc1 = (const float*)d_in[4];
  const float* Wf2 = (const float*)d_in[5];
  const float* bf2 = (const float*)d_in[6];
  const float* Wc2 = (const float*)d_in[7];
  const float* bc2 = (const float*)d_in[8];
  float* out = (float*)d_out;

  char* ws = (char*)d_ws;
  f16*  Xg   = (f16*)(ws);                          // 64*1024*512*2  = 67108864 B
  f16*  y1h  = (f16*)(ws + 67108864);               // 64*1024*256*2  = 33554432 B
  f16*  Wx1T = (f16*)(ws + 100663296);              // 512*128*2      = 131072 B
  f16*  Wx2T = (f16*)(ws + 100794368);              // 512*256*2      = 262144 B
  int*  sync = (int*)(ws + 101056512);              // 261 ints

  float* y2   = out;                                // [64,1024,256]
  float* hid1 = out + (size_t)B_ * T_ * H_;         // [64,256]
  float* hid2 = hid1 + (size_t)B_ * H_;             // [64,256]

  hipMemsetAsync(sync, 0, 261 * sizeof(int), stream);
  fused<<<72, 512, 0, stream>>>(x, Wf1, bf1, Wc1, bc1, Wf2, bf2, Wc2, bc2,
                                Xg, Wx1T, Wx2T, y1h, y2, hid1, hid2, sync);
}